// Round 9
// baseline (550.013 us; speedup 1.0000x reference)
//
#include <hip/hip_runtime.h>

typedef unsigned short u16;
typedef unsigned int u32;

typedef __bf16 bf16x8 __attribute__((ext_vector_type(8)));
typedef float f32x4 __attribute__((ext_vector_type(4)));
typedef u16 u16x8 __attribute__((ext_vector_type(8)));

#define TSEQ 4096
#define DDIM 1024
#define NB 4
#define EPSV 1e-6f
// bounce-buffer row pitch in u16 (272 B = 17*16 -> rows stay 16B-aligned, banks rotate)
#define CPITCH 136
// 256^2 epilogue bounce pitch (u16): 528 B rows, 16B-aligned, banks rotate by 4
#define EPITCH 264

__device__ __forceinline__ u16 f2b(float f) {
    union { float f; u32 u; } v; v.f = f;
    u32 r = v.u + 0x7FFFu + ((v.u >> 16) & 1u);
    return (u16)(r >> 16);
}
__device__ __forceinline__ float b2f(u16 h) {
    union { u32 u; float f; } v; v.u = ((u32)h) << 16; return v.f;
}
__device__ __forceinline__ u16 f2h(float f) {
    union { _Float16 h; u16 u; } v; v.h = (_Float16)f; return v.u;
}
__device__ __forceinline__ float h2f(u16 u) {
    union { u16 u; _Float16 h; } v; v.u = u; return (float)v.h;
}

// ---------------- merged prep: x->bf16, W->bf16 concat, bias concat, denom zero ----
__global__ __launch_bounds__(256) void k_prep(
    const float* __restrict__ x,
    const float* __restrict__ wq, const float* __restrict__ wk,
    const float* __restrict__ wv, const float* __restrict__ wa,
    const float* __restrict__ bq, const float* __restrict__ bk,
    const float* __restrict__ bv, const float* __restrict__ ba,
    u16* __restrict__ xw, u16* __restrict__ wcat, float* __restrict__ bcat,
    float* __restrict__ denom) {
    int bid = blockIdx.x, tid = threadIdx.x;
    if (bid < 1024) {
        size_t base = (size_t)bid * 4096 + tid;
#pragma unroll
        for (int k = 0; k < 16; ++k) {
            size_t f4 = base + k * 256;
            float4 f = ((const float4*)x)[f4];
            ushort4 u;
            u.x = f2b(f.x); u.y = f2b(f.y); u.z = f2b(f.z); u.w = f2b(f.w);
            *(ushort4*)(xw + f4 * 4) = u;
        }
    } else if (bid < 1280) {
        size_t base = (size_t)(bid - 1024) * 4096 + tid;
#pragma unroll
        for (int k = 0; k < 16; ++k) {
            size_t f4 = base + k * 256;
            int sel = (int)(f4 >> 18);
            const float* src = (sel == 0) ? wq : (sel == 1) ? wk : (sel == 2) ? wv : wa;
            float4 f = ((const float4*)src)[f4 & 262143];
            ushort4 u;
            u.x = f2b(f.x); u.y = f2b(f.y); u.z = f2b(f.z); u.w = f2b(f.w);
            *(ushort4*)(wcat + f4 * 4) = u;
        }
    } else if (bid == 1280) {
#pragma unroll
        for (int c = 0; c < 16; ++c) {
            int j = c * 256 + tid;
            int sel = j >> 10;
            const float* src = (sel == 0) ? bq : (sel == 1) ? bk : (sel == 2) ? bv : ba;
            bcat[j] = src[j & 1023];
        }
    } else {
        float4 z = {0.f, 0.f, 0.f, 0.f};
#pragma unroll
        for (int k = 0; k < 16; ++k)
            ((float4*)denom)[k * 256 + tid] = z;
    }
}

// ---------------- GEMM core helpers (k_scores / k_num, 128^2 structure) -----------
__device__ __forceinline__ void stage_k(u16* __restrict__ dst, const char* __restrict__ base,
                                        int ld2, int kbyte, int wid, int lane) {
#pragma unroll
    for (int c = 0; c < 4; ++c) {
        const char* g = base + c * 8 * ld2 + kbyte;
        char* l = (char*)dst + (wid * 32 + c * 8) * 128 + lane * 16;
        __builtin_amdgcn_global_load_lds((const __attribute__((address_space(1))) u32*)g,
                                         (__attribute__((address_space(3))) u32*)l, 16, 0, 0);
    }
}

__device__ __forceinline__ void mma_tile(const u16* __restrict__ As, const u16* __restrict__ Bs,
                                         f32x4 acc[4][4], int wm, int wn, int quad, int l15) {
#pragma unroll
    for (int kk = 0; kk < 64; kk += 32) {
        int cg = (kk >> 3) + quad;
        bf16x8 a[4], b[4];
#pragma unroll
        for (int i = 0; i < 4; ++i) {
            int arow = wm * 64 + i * 16 + l15;
            int brow = wn * 64 + i * 16 + l15;
            a[i] = *(const bf16x8*)(As + arow * 64 + ((cg ^ (arow & 7)) << 3));
            b[i] = *(const bf16x8*)(Bs + brow * 64 + ((cg ^ (brow & 7)) << 3));
        }
#pragma unroll
        for (int i = 0; i < 4; ++i)
#pragma unroll
            for (int j = 0; j < 4; ++j)
                acc[i][j] = __builtin_amdgcn_mfma_f32_16x16x32_bf16(a[i], b[j], acc[i][j], 0, 0, 0);
    }
}

#define KVM0_ asm volatile("s_waitcnt vmcnt(0)" ::: "memory")
#define KBAR_ __builtin_amdgcn_s_barrier()

// ---------------- fused QKVA projection GEMM: 256^2 tile, 2 barrier-pairs/K-tile --
// Round 17 structure (kept; R12-R17 established a ~199us plateau: time tracks
// staged bytes regardless of barrier density / read count / VALU -> stage-service
// bound at 1 block/CU with no TLP; 256^2 cannot fit 2 blocks/CU (acc=128 VGPR).
// Parked). See R17 comment history for the ledger derivation.
#define STG_A(dst_d, dst_h, kofs) do { \
    const char* _g = gAt + ((dst_h) * 262144 + wid * 32768 + (kofs)); \
    char* _l = lA + ((dst_d) * 32768 + (dst_h) * 16384); \
    __builtin_amdgcn_global_load_lds((const __attribute__((address_space(1))) u32*)_g, \
        (__attribute__((address_space(3))) u32*)_l, 16, 0, 0); \
    __builtin_amdgcn_global_load_lds((const __attribute__((address_space(1))) u32*)(_g + 16384), \
        (__attribute__((address_space(3))) u32*)(_l + 1024), 16, 0, 0); \
  } while (0)

#define STG_B(dst_d, dst_h, kofs) do { \
    const char* _g = gBt + ((dst_h) * 262144 + wid * 32768 + (kofs)); \
    char* _l = lB + ((dst_d) * 32768 + (dst_h) * 16384); \
    __builtin_amdgcn_global_load_lds((const __attribute__((address_space(1))) u32*)_g, \
        (__attribute__((address_space(3))) u32*)_l, 16, 0, 0); \
    __builtin_amdgcn_global_load_lds((const __attribute__((address_space(1))) u32*)(_g + 16384), \
        (__attribute__((address_space(3))) u32*)(_l + 1024), 16, 0, 0); \
  } while (0)

#define NOP_ ((void)0)
#define VM0_ asm volatile("s_waitcnt vmcnt(0)" ::: "memory")
#define VM4_ asm volatile("s_waitcnt vmcnt(4)" ::: "memory")
#define BAR_ __builtin_amdgcn_s_barrier()
#define LGK_ asm volatile("s_waitcnt lgkmcnt(0)" ::: "memory")
#define SB0_ __builtin_amdgcn_sched_barrier(0)

#define LDA(hh, dd) do { \
    _Pragma("unroll") \
    for (int _i = 0; _i < 4; ++_i) { \
      Ar[_i][0] = *(const bf16x8*)(pA0 + ((dd) * 16384 + (hh) * 8192 + _i * 1024)); \
      Ar[_i][1] = *(const bf16x8*)(pA1 + ((dd) * 16384 + (hh) * 8192 + _i * 1024)); \
    } } while (0)

#define LDB(hh, dd) do { \
    _Pragma("unroll") \
    for (int _j = 0; _j < 2; ++_j) { \
      Br[hh][_j][0] = *(const bf16x8*)(pB0 + ((dd) * 16384 + (hh) * 8192 + _j * 1024)); \
      Br[hh][_j][1] = *(const bf16x8*)(pB1 + ((dd) * 16384 + (hh) * 8192 + _j * 1024)); \
    } } while (0)

#define MMA(qa, qb) do { \
    __builtin_amdgcn_s_setprio(1); \
    _Pragma("unroll") \
    for (int _kk = 0; _kk < 2; ++_kk) \
      _Pragma("unroll") \
      for (int _i = 0; _i < 4; ++_i) \
        _Pragma("unroll") \
        for (int _j = 0; _j < 2; ++_j) \
          acc[(qa) * 4 + _i][(qb) * 2 + _j] = __builtin_amdgcn_mfma_f32_16x16x32_bf16( \
              Ar[_i][_kk], Br[qb][_j][_kk], acc[(qa) * 4 + _i][(qb) * 2 + _j], 0, 0, 0); \
    __builtin_amdgcn_s_setprio(0); \
  } while (0)

__global__ __launch_bounds__(512, 2) void k_gemm_qkva(
    const u16* __restrict__ xw, const u16* __restrict__ wcat, const float* __restrict__ bcat,
    u16* __restrict__ qb, u16* __restrict__ kb, u16* __restrict__ vT, u16* __restrict__ gA,
    float* __restrict__ part) {
    __shared__ __align__(16) char smem[131072];  // A[2][2][128][64] | B[2][2][128][64]
    u16* As = (u16*)smem;
    u16* Bs = (u16*)(smem + 65536);
    int tid = threadIdx.x;
    int wid = tid >> 6, lane = tid & 63;
    int wm = wid >> 2, wn = wid & 3;          // 2 x 4 wave grid
    int quad = lane >> 4, l15 = lane & 15;
    int g8 = lane >> 3, hx = (lane & 7) ^ g8;
    size_t m0 = (size_t)blockIdx.x * 256, n0 = (size_t)blockIdx.y * 256;  // m fastest (XCD pin)
    const char* gAp = (const char*)xw + (m0 + g8) * 2048 + hx * 16;
    const char* gBp = (const char*)wcat + (n0 + g8) * 2048 + hx * 16;
    char* lA = smem + wid * 2048 + lane * 16;
    char* lB = smem + 65536 + wid * 2048 + lane * 16;

    int x0 = (quad ^ (l15 & 7)) << 3;
    int x1 = ((quad + 4) ^ (l15 & 7)) << 3;
    const u16* pA0 = As + (wm * 64 + l15) * 64 + x0;
    const u16* pA1 = As + (wm * 64 + l15) * 64 + x1;
    const u16* pB0 = Bs + (wn * 32 + l15) * 64 + x0;
    const u16* pB1 = Bs + (wn * 32 + l15) * 64 + x1;

    f32x4 acc[8][4] = {};
    bf16x8 Ar[4][2];
    bf16x8 Br[2][2][2];

    const char* gAt = gAp;
    const char* gBt = gBp;

    STG_A(0, 0, 0); STG_B(0, 0, 0);
    STG_A(0, 1, 0); STG_B(0, 1, 0);
    STG_A(1, 0, 128); STG_B(1, 0, 128);
    VM4_;
    BAR_;

#pragma unroll 2
    for (int t = 0; t < 14; ++t) {
        int d = t & 1, dn = d ^ 1;
        LDA(0, d); LDB(0, d); LDB(1, d);
        STG_A(dn, 1, 128); STG_B(dn, 1, 128);
        BAR_; LGK_; SB0_; MMA(0, 0); MMA(0, 1); BAR_;
        LDA(1, d);
        STG_A(d, 0, 256); STG_B(d, 0, 256);
        BAR_; LGK_; SB0_; MMA(1, 0); MMA(1, 1); VM4_; BAR_;
        gAt += 128; gBt += 128;
    }
    {
        LDA(0, 0); LDB(0, 0); LDB(1, 0);
        STG_A(1, 1, 128); STG_B(1, 1, 128);
        BAR_; LGK_; SB0_; MMA(0, 0); MMA(0, 1); BAR_;
        LDA(1, 0);
        BAR_; LGK_; SB0_; MMA(1, 0); MMA(1, 1); VM0_; BAR_;
    }
    {
        LDA(0, 1); LDB(0, 1); LDB(1, 1);
        BAR_; LGK_; SB0_; MMA(0, 0); MMA(0, 1); BAR_;
        LDA(1, 1);
        BAR_; LGK_; SB0_; MMA(1, 0); MMA(1, 1); BAR_;
    }

    // ---------------- epilogue: two 128-row bounce rounds through LDS -------------
    int blk = (int)(n0 >> 10), nf0 = (int)(n0 & 1023);
    int bB = (int)(m0 >> 12), t0m = (int)(m0 & 4095);
    float bias[4];
#pragma unroll
    for (int j = 0; j < 4; ++j)
        bias[j] = bcat[n0 + (size_t)((j >> 1) * 128 + wn * 32 + (j & 1) * 16 + l15)];
    u16* Cs = (u16*)smem;

#pragma unroll
    for (int h = 0; h < 2; ++h) {
        if (h) __syncthreads();
#pragma unroll
        for (int j = 0; j < 4; ++j) {
            float cs = 0.f;
            int col = (j >> 1) * 128 + wn * 32 + (j & 1) * 16 + l15;
#pragma unroll
            for (int i4 = 0; i4 < 4; ++i4) {
#pragma unroll
                for (int r = 0; r < 4; ++r) {
                    float z = acc[h * 4 + i4][j][r] + bias[j];
                    u16 o;
                    if (blk < 2) {
                        o = f2b(fmaxf(z, 0.f));
                    } else if (blk == 2) {
                        o = f2b(z);
                    } else {
                        float gg = __logf(1.f / (1.f + __expf(-z)) + 1e-6f);
                        o = f2h(gg);
                        cs += gg;
                    }
                    Cs[(wm * 64 + i4 * 16 + quad * 4 + r) * EPITCH + col] = o;
                }
            }
            if (blk == 3) {
                cs += __shfl_xor(cs, 16, 64);
                cs += __shfl_xor(cs, 32, 64);
                if (quad == 0) {
                    int chunk = (t0m >> 6) + h * 2 + wm;
                    part[((size_t)(bB * 64 + chunk) << 10) + nf0 + col] = cs;
                }
            }
        }
        __syncthreads();
        if (blk != 2) {
            u16* dst = (blk == 0) ? qb : (blk == 1) ? kb : gA;
            int lr = tid >> 2, c0 = (tid & 3) * 64;
            size_t rowo = (size_t)(m0 + h * 128 + lr) * 1024 + nf0 + c0;
#pragma unroll
            for (int i = 0; i < 8; ++i)
                *(u16x8*)(dst + rowo + i * 8) = *(const u16x8*)(Cs + lr * EPITCH + c0 + i * 8);
        } else {
            int jc = tid >> 1, th = (tid & 1) * 64;
            size_t rowo = (((size_t)(bB * 1024 + nf0 + jc)) << 12) + t0m + h * 128 + th;
#pragma unroll
            for (int i = 0; i < 8; ++i) {
                u16x8 vv;
#pragma unroll
                for (int e = 0; e < 8; ++e)
                    vv[e] = Cs[(th + i * 8 + e) * EPITCH + jc];
                *(u16x8*)(vT + rowo + i * 8) = vv;
            }
        }
    }
}

// ---------------- gate scan apply (fused suffix-sum of raw chunk partials) ----------
// Round 19: vectorized 4 cols/thread (ushort4 = 8B/lane, Guideline 13). Old version
// did 64 serial iterations of SCALAR u16 loads/stores (2B/lane) + expf: if
// issue-bound, /4 the instruction count; 4 independent r-chains also improve ILP
// on the serial suffix recurrence. Traffic unchanged (96 MB, floor ~16-20us).
// Grid (64, NB) = 256 blocks = 1/CU; math per column identical to R11 version.
__global__ __launch_bounds__(256) void k_scan_apply(
    const u16* __restrict__ gA, const float* __restrict__ part, u16* __restrict__ kb) {
    int c = blockIdx.x, b = blockIdx.y;
    int col = threadIdx.x * 4;
    float4 r = {0.f, 0.f, 0.f, 0.f};
    for (int c2 = c + 1; c2 < 64; ++c2) {
        float4 p = *(const float4*)(part + ((size_t)(b * 64 + c2) << 10) + col);
        r.x += p.x; r.y += p.y; r.z += p.z; r.w += p.w;
    }
    size_t base = (((size_t)(b * TSEQ + c * 64)) << 10) + col;
#pragma unroll 4
    for (int s = 63; s >= 0; --s) {
        size_t ro = base + ((size_t)s << 10);
        ushort4 g = *(const ushort4*)(gA + ro);
        ushort4 kv = *(const ushort4*)(kb + ro);
        r.x += h2f(g.x); r.y += h2f(g.y); r.z += h2f(g.z); r.w += h2f(g.w);
        ushort4 o;
        o.x = f2b(b2f(kv.x) * __expf(r.x));
        o.y = f2b(b2f(kv.y) * __expf(r.y));
        o.z = f2b(b2f(kv.z) * __expf(r.z));
        o.w = f2b(b2f(kv.w) * __expf(r.w));
        *(ushort4*)(kb + ro) = o;
    }
}

// ---------------- scores = q @ wk^T (causal), bf16 out + denom atomics ----------------
// Round 18 structure kept (dbuf 2-phase; >= R17 by 8us).
__global__ __launch_bounds__(256) void k_scores(
    const u16* __restrict__ qb, const u16* __restrict__ wkb,
    u16* __restrict__ scores, float* __restrict__ denom) {
    int bid = blockIdx.x, b = blockIdx.y;
    int xc = bid & 7, idx = bid >> 3;          // idx in [0, 66)
    int rs0 = xc, rs1 = 15 - xc, rs2 = 16 + xc, rs3 = 31 - xc;  // ascending
    int si = 0, rem = idx;
    for (; si < 32; ++si) {
        int n = (rs0 >= si) + (rs1 >= si) + (rs2 >= si) + (rs3 >= si);
        if (rem < n) break;
        rem -= n;
    }
    int ti = rs3, cnt = 0;
    if (rs0 >= si) { if (cnt == rem) ti = rs0; ++cnt; }
    if (rs1 >= si) { if (cnt == rem) ti = rs1; ++cnt; }
    if (rs2 >= si) { if (cnt == rem) ti = rs2; ++cnt; }
    if (rs3 >= si) { if (cnt == rem) ti = rs3; ++cnt; }
    __shared__ __align__(16) char smem[65536];  // A[2][128][64] | B[2][128][64]; bounce overlays
    u16* As = (u16*)smem;
    u16* Bs = (u16*)(smem + 32768);
    int tid = threadIdx.x;
    const u16* A = qb + ((size_t)b << 22);
    const u16* Bm = wkb + ((size_t)b << 22);
    int t0 = ti * 128, s0 = si * 128;
    int wid = tid >> 6, lane = tid & 63;
    int wm = wid >> 1, wn = wid & 1, quad = lane >> 4, l15 = lane & 15;
    int hxor = (lane & 7) ^ (lane >> 3);
    const char* baA = (const char*)A + (size_t)(t0 + wid * 32 + (lane >> 3)) * 2048 + hxor * 16;
    const char* baB = (const char*)Bm + (size_t)(s0 + wid * 32 + (lane >> 3)) * 2048 + hxor * 16;
    f32x4 acc[4][4] = {};
    stage_k(As, baA, 2048, 0, wid, lane);
    stage_k(Bs, baB, 2048, 0, wid, lane);
    KVM0_; KBAR_;
#pragma unroll 2
    for (int t = 0; t < 16; ++t) {
        int cur = t & 1;
        if (t < 15) {
            stage_k(As + (cur ^ 1) * 8192, baA, 2048, (t + 1) * 128, wid, lane);
            stage_k(Bs + (cur ^ 1) * 8192, baB, 2048, (t + 1) * 128, wid, lane);
        }
        mma_tile(As + cur * 8192, Bs + cur * 8192, acc, wm, wn, quad, l15);
        KVM0_; KBAR_;
    }
    u16* Cs = (u16*)smem;
#pragma unroll
    for (int im = 0; im < 4; ++im) {
#pragma unroll
        for (int r = 0; r < 4; ++r) {
            int trow = t0 + wm * 64 + im * 16 + quad * 4 + r;
            float rs = 0.f;
#pragma unroll
            for (int jn = 0; jn < 4; ++jn) {
                int s = s0 + wn * 64 + jn * 16 + l15;
                float val = acc[im][jn][r];
                if (s > trow) val = 0.f;
                rs += val;
                Cs[(wm * 64 + im * 16 + quad * 4 + r) * CPITCH + wn * 64 + jn * 16 + l15] = f2b(val);
            }
#pragma unroll
            for (int m = 1; m < 16; m <<= 1) rs += __shfl_xor(rs, m, 64);
            if (l15 == 0) atomicAdd(denom + (b << 12) + trow, rs);
        }
    }
    __syncthreads();
    int r = tid >> 1, ch = (tid & 1) * 64;
    size_t rowo = ((size_t)(b * TSEQ + t0 + r) << 12) + s0 + ch;
#pragma unroll
    for (int i = 0; i < 8; ++i)
        *(u16x8*)(scores + rowo + i * 8) = *(const u16x8*)(Cs + r * CPITCH + ch + i * 8);
}

// ---------------- num = scores @ v (causal K bound), divide by denom ----------------
// Round 18 structure kept (dbuf 2-phase).
__global__ __launch_bounds__(256) void k_num(
    const u16* __restrict__ scores, const u16* __restrict__ vT,
    const float* __restrict__ denom, float* __restrict__ out) {
    int ji = blockIdx.x, ti = 31 - blockIdx.y, b = blockIdx.z;
    __shared__ __align__(16) char smem[65536];  // A[2][128][64] | B[2][128][64]
    u16* As = (u16*)smem;
    u16* Bs = (u16*)(smem + 32768);
    int tid = threadIdx.x;
    const u16* A = scores + ((size_t)b << 24);  // [T][T]
    const u16* Bm = vT + ((size_t)b << 22);     // [D][T]
    int t0 = ti * 128, j0 = ji * 128;
    int wid = tid >> 6, lane = tid & 63;
    int wm = wid >> 1, wn = wid & 1, quad = lane >> 4, l15 = lane & 15;
    int hxor = (lane & 7) ^ (lane >> 3);
    const char* pA = (const char*)A + (size_t)(t0 + wid * 32 + (lane >> 3)) * 8192 + hxor * 16;
    const char* pB = (const char*)Bm + (size_t)(j0 + wid * 32 + (lane >> 3)) * 8192 + hxor * 16;
    f32x4 acc[4][4] = {};
    int nt = (ti + 1) * 2;  // BK=64 tiles
    stage_k(As, pA, 8192, 0, wid, lane);
    stage_k(Bs, pB, 8192, 0, wid, lane);
    KVM0_; KBAR_;
    for (int t = 0; t < nt; ++t) {
        int cur = t & 1;
        if (t + 1 < nt) {
            stage_k(As + (cur ^ 1) * 8192, pA, 8192, (t + 1) * 128, wid, lane);
            stage_k(Bs + (cur ^ 1) * 8192, pB, 8192, (t + 1) * 128, wid, lane);
        }
        mma_tile(As + cur * 8192, Bs + cur * 8192, acc, wm, wn, quad, l15);
        KVM0_; KBAR_;
    }
#pragma unroll
    for (int im = 0; im < 4; ++im) {
#pragma unroll
        for (int r = 0; r < 4; ++r) {
            int t = t0 + wm * 64 + im * 16 + quad * 4 + r;
            float den = denom[(b << 12) + t] + EPSV;
#pragma unroll
            for (int jn = 0; jn < 4; ++jn) {
                int j = j0 + wn * 64 + jn * 16 + l15;
                out[((size_t)(b * TSEQ + t) << 10) + j] = acc[im][jn][r] / den;
            }
        }
    }
}

// ---------------- workspace layout (bytes) ----------------
static const size_t OFF_Q      = 0;
static const size_t OFF_WK     = 33554432;
static const size_t OFF_VT     = 67108864;
static const size_t OFF_DENOM  = 100663296;
static const size_t OFF_BCAT   = 100728832;
static const size_t OFF_XW     = 100745216;
static const size_t OFF_WCAT   = 134299648;
static const size_t OFF_GA     = 176242688;   // f16: 33.5 MB
static const size_t OFF_PART   = 243351552;
static const size_t OFF_SCORES = OFF_XW;  // 134,217,728 B, overlays dead early region

extern "C" void kernel_launch(void* const* d_in, const int* in_sizes, int n_in,
                              void* d_out, int out_size, void* d_ws, size_t ws_size,
                              hipStream_t stream) {
    const float* x  = (const float*)d_in[0];
    const float* Wq = (const float*)d_in[1];
    const float* bq = (const float*)d_in[2];
    const float* Wk = (const float*)d_in[3];
    const float* bk = (const float*)d_in[4];
    const float* Wv = (const float*)d_in[5];
    const float* bv = (const float*)d_in[6];
    const float* Wa = (const float*)d_in[7];
    const float* ba = (const float*)d_in[8];
    float* out = (float*)d_out;

    char* W = (char*)d_ws;
    u16* qb      = (u16*)(W + OFF_Q);
    u16* wkb     = (u16*)(W + OFF_WK);
    u16* vT      = (u16*)(W + OFF_VT);
    float* denom = (float*)(W + OFF_DENOM);
    float* bcat  = (float*)(W + OFF_BCAT);
    u16* xw      = (u16*)(W + OFF_XW);
    u16* wcat    = (u16*)(W + OFF_WCAT);
    u16* gA      = (u16*)(W + OFF_GA);
    float* part  = (float*)(W + OFF_PART);
    u16* scores  = (u16*)(W + OFF_SCORES);

    k_prep<<<1282, 256, 0, stream>>>(x, Wq, Wk, Wv, Wa, bq, bk, bv, ba, xw, wcat, bcat, denom);

    k_gemm_qkva<<<dim3(64, 16), 512, 0, stream>>>(xw, wcat, bcat, qb, wkb, vT, gA, part);

    k_scan_apply<<<dim3(64, NB), 256, 0, stream>>>(gA, part, wkb);

    k_scores<<<dim3(528, NB), 256, 0, stream>>>(qb, wkb, scores, denom);

    k_num<<<dim3(8, 32, NB), 256, 0, stream>>>(scores, vT, denom, out);
}

// Round 10
// 536.112 us; speedup vs baseline: 1.0259x; 1.0259x over previous
//
#include <hip/hip_runtime.h>

typedef unsigned short u16;
typedef unsigned int u32;

typedef __bf16 bf16x8 __attribute__((ext_vector_type(8)));
typedef float f32x4 __attribute__((ext_vector_type(4)));
typedef u16 u16x8 __attribute__((ext_vector_type(8)));

#define TSEQ 4096
#define DDIM 1024
#define NB 4
#define EPSV 1e-6f
// bounce-buffer row pitch in u16 (272 B = 17*16 -> rows stay 16B-aligned, banks rotate)
#define CPITCH 136
// 256^2 epilogue bounce pitch (u16): 528 B rows, 16B-aligned, banks rotate by 4
#define EPITCH 264

__device__ __forceinline__ u16 f2b(float f) {
    union { float f; u32 u; } v; v.f = f;
    u32 r = v.u + 0x7FFFu + ((v.u >> 16) & 1u);
    return (u16)(r >> 16);
}
__device__ __forceinline__ float b2f(u16 h) {
    union { u32 u; float f; } v; v.u = ((u32)h) << 16; return v.f;
}
__device__ __forceinline__ u16 f2h(float f) {
    union { _Float16 h; u16 u; } v; v.h = (_Float16)f; return v.u;
}
__device__ __forceinline__ float h2f(u16 u) {
    union { u16 u; _Float16 h; } v; v.u = u; return (float)v.h;
}

// ---------------- merged prep: x->bf16, W->bf16 concat, bias concat, denom zero ----
__global__ __launch_bounds__(256) void k_prep(
    const float* __restrict__ x,
    const float* __restrict__ wq, const float* __restrict__ wk,
    const float* __restrict__ wv, const float* __restrict__ wa,
    const float* __restrict__ bq, const float* __restrict__ bk,
    const float* __restrict__ bv, const float* __restrict__ ba,
    u16* __restrict__ xw, u16* __restrict__ wcat, float* __restrict__ bcat,
    float* __restrict__ denom) {
    int bid = blockIdx.x, tid = threadIdx.x;
    if (bid < 1024) {
        size_t base = (size_t)bid * 4096 + tid;
#pragma unroll
        for (int k = 0; k < 16; ++k) {
            size_t f4 = base + k * 256;
            float4 f = ((const float4*)x)[f4];
            ushort4 u;
            u.x = f2b(f.x); u.y = f2b(f.y); u.z = f2b(f.z); u.w = f2b(f.w);
            *(ushort4*)(xw + f4 * 4) = u;
        }
    } else if (bid < 1280) {
        size_t base = (size_t)(bid - 1024) * 4096 + tid;
#pragma unroll
        for (int k = 0; k < 16; ++k) {
            size_t f4 = base + k * 256;
            int sel = (int)(f4 >> 18);
            const float* src = (sel == 0) ? wq : (sel == 1) ? wk : (sel == 2) ? wv : wa;
            float4 f = ((const float4*)src)[f4 & 262143];
            ushort4 u;
            u.x = f2b(f.x); u.y = f2b(f.y); u.z = f2b(f.z); u.w = f2b(f.w);
            *(ushort4*)(wcat + f4 * 4) = u;
        }
    } else if (bid == 1280) {
#pragma unroll
        for (int c = 0; c < 16; ++c) {
            int j = c * 256 + tid;
            int sel = j >> 10;
            const float* src = (sel == 0) ? bq : (sel == 1) ? bk : (sel == 2) ? bv : ba;
            bcat[j] = src[j & 1023];
        }
    } else {
        float4 z = {0.f, 0.f, 0.f, 0.f};
#pragma unroll
        for (int k = 0; k < 16; ++k)
            ((float4*)denom)[k * 256 + tid] = z;
    }
}

// ---------------- GEMM core helpers (k_scores / k_num, 128^2 structure) -----------
__device__ __forceinline__ void stage_k(u16* __restrict__ dst, const char* __restrict__ base,
                                        int ld2, int kbyte, int wid, int lane) {
#pragma unroll
    for (int c = 0; c < 4; ++c) {
        const char* g = base + c * 8 * ld2 + kbyte;
        char* l = (char*)dst + (wid * 32 + c * 8) * 128 + lane * 16;
        __builtin_amdgcn_global_load_lds((const __attribute__((address_space(1))) u32*)g,
                                         (__attribute__((address_space(3))) u32*)l, 16, 0, 0);
    }
}

// Round 20: s_setprio(1) around the MFMA cluster (T5, regime-matched: scores/num
// run 2-5 INDEPENDENT blocks/CU -> CU scheduler has load-issuing vs MFMA-entering
// waves to arbitrate; this is m191's winning regime, not m190's lockstep null).
__device__ __forceinline__ void mma_tile(const u16* __restrict__ As, const u16* __restrict__ Bs,
                                         f32x4 acc[4][4], int wm, int wn, int quad, int l15) {
#pragma unroll
    for (int kk = 0; kk < 64; kk += 32) {
        int cg = (kk >> 3) + quad;
        bf16x8 a[4], b[4];
#pragma unroll
        for (int i = 0; i < 4; ++i) {
            int arow = wm * 64 + i * 16 + l15;
            int brow = wn * 64 + i * 16 + l15;
            a[i] = *(const bf16x8*)(As + arow * 64 + ((cg ^ (arow & 7)) << 3));
            b[i] = *(const bf16x8*)(Bs + brow * 64 + ((cg ^ (brow & 7)) << 3));
        }
        __builtin_amdgcn_s_setprio(1);
#pragma unroll
        for (int i = 0; i < 4; ++i)
#pragma unroll
            for (int j = 0; j < 4; ++j)
                acc[i][j] = __builtin_amdgcn_mfma_f32_16x16x32_bf16(a[i], b[j], acc[i][j], 0, 0, 0);
        __builtin_amdgcn_s_setprio(0);
    }
}

#define KVM0_ asm volatile("s_waitcnt vmcnt(0)" ::: "memory")
#define KBAR_ __builtin_amdgcn_s_barrier()

// ---------------- fused QKVA projection GEMM: 256^2 tile, 2 barrier-pairs/K-tile --
// R17 structure (parked at ~199us: stage-path L2-capacity bound; 7 schedule
// variants bracket 199-238; time tracks staged bytes).
#define STG_A(dst_d, dst_h, kofs) do { \
    const char* _g = gAt + ((dst_h) * 262144 + wid * 32768 + (kofs)); \
    char* _l = lA + ((dst_d) * 32768 + (dst_h) * 16384); \
    __builtin_amdgcn_global_load_lds((const __attribute__((address_space(1))) u32*)_g, \
        (__attribute__((address_space(3))) u32*)_l, 16, 0, 0); \
    __builtin_amdgcn_global_load_lds((const __attribute__((address_space(1))) u32*)(_g + 16384), \
        (__attribute__((address_space(3))) u32*)(_l + 1024), 16, 0, 0); \
  } while (0)

#define STG_B(dst_d, dst_h, kofs) do { \
    const char* _g = gBt + ((dst_h) * 262144 + wid * 32768 + (kofs)); \
    char* _l = lB + ((dst_d) * 32768 + (dst_h) * 16384); \
    __builtin_amdgcn_global_load_lds((const __attribute__((address_space(1))) u32*)_g, \
        (__attribute__((address_space(3))) u32*)_l, 16, 0, 0); \
    __builtin_amdgcn_global_load_lds((const __attribute__((address_space(1))) u32*)(_g + 16384), \
        (__attribute__((address_space(3))) u32*)(_l + 1024), 16, 0, 0); \
  } while (0)

#define NOP_ ((void)0)
#define VM0_ asm volatile("s_waitcnt vmcnt(0)" ::: "memory")
#define VM4_ asm volatile("s_waitcnt vmcnt(4)" ::: "memory")
#define BAR_ __builtin_amdgcn_s_barrier()
#define LGK_ asm volatile("s_waitcnt lgkmcnt(0)" ::: "memory")
#define SB0_ __builtin_amdgcn_sched_barrier(0)

#define LDA(hh, dd) do { \
    _Pragma("unroll") \
    for (int _i = 0; _i < 4; ++_i) { \
      Ar[_i][0] = *(const bf16x8*)(pA0 + ((dd) * 16384 + (hh) * 8192 + _i * 1024)); \
      Ar[_i][1] = *(const bf16x8*)(pA1 + ((dd) * 16384 + (hh) * 8192 + _i * 1024)); \
    } } while (0)

#define LDB(hh, dd) do { \
    _Pragma("unroll") \
    for (int _j = 0; _j < 2; ++_j) { \
      Br[hh][_j][0] = *(const bf16x8*)(pB0 + ((dd) * 16384 + (hh) * 8192 + _j * 1024)); \
      Br[hh][_j][1] = *(const bf16x8*)(pB1 + ((dd) * 16384 + (hh) * 8192 + _j * 1024)); \
    } } while (0)

#define MMA(qa, qb) do { \
    __builtin_amdgcn_s_setprio(1); \
    _Pragma("unroll") \
    for (int _kk = 0; _kk < 2; ++_kk) \
      _Pragma("unroll") \
      for (int _i = 0; _i < 4; ++_i) \
        _Pragma("unroll") \
        for (int _j = 0; _j < 2; ++_j) \
          acc[(qa) * 4 + _i][(qb) * 2 + _j] = __builtin_amdgcn_mfma_f32_16x16x32_bf16( \
              Ar[_i][_kk], Br[qb][_j][_kk], acc[(qa) * 4 + _i][(qb) * 2 + _j], 0, 0, 0); \
    __builtin_amdgcn_s_setprio(0); \
  } while (0)

__global__ __launch_bounds__(512, 2) void k_gemm_qkva(
    const u16* __restrict__ xw, const u16* __restrict__ wcat, const float* __restrict__ bcat,
    u16* __restrict__ qb, u16* __restrict__ kb, u16* __restrict__ vT, u16* __restrict__ gA,
    float* __restrict__ part) {
    __shared__ __align__(16) char smem[131072];  // A[2][2][128][64] | B[2][2][128][64]
    u16* As = (u16*)smem;
    u16* Bs = (u16*)(smem + 65536);
    int tid = threadIdx.x;
    int wid = tid >> 6, lane = tid & 63;
    int wm = wid >> 2, wn = wid & 3;          // 2 x 4 wave grid
    int quad = lane >> 4, l15 = lane & 15;
    int g8 = lane >> 3, hx = (lane & 7) ^ g8;
    size_t m0 = (size_t)blockIdx.x * 256, n0 = (size_t)blockIdx.y * 256;  // m fastest (XCD pin)
    const char* gAp = (const char*)xw + (m0 + g8) * 2048 + hx * 16;
    const char* gBp = (const char*)wcat + (n0 + g8) * 2048 + hx * 16;
    char* lA = smem + wid * 2048 + lane * 16;
    char* lB = smem + 65536 + wid * 2048 + lane * 16;

    int x0 = (quad ^ (l15 & 7)) << 3;
    int x1 = ((quad + 4) ^ (l15 & 7)) << 3;
    const u16* pA0 = As + (wm * 64 + l15) * 64 + x0;
    const u16* pA1 = As + (wm * 64 + l15) * 64 + x1;
    const u16* pB0 = Bs + (wn * 32 + l15) * 64 + x0;
    const u16* pB1 = Bs + (wn * 32 + l15) * 64 + x1;

    f32x4 acc[8][4] = {};
    bf16x8 Ar[4][2];
    bf16x8 Br[2][2][2];

    const char* gAt = gAp;
    const char* gBt = gBp;

    STG_A(0, 0, 0); STG_B(0, 0, 0);
    STG_A(0, 1, 0); STG_B(0, 1, 0);
    STG_A(1, 0, 128); STG_B(1, 0, 128);
    VM4_;
    BAR_;

#pragma unroll 2
    for (int t = 0; t < 14; ++t) {
        int d = t & 1, dn = d ^ 1;
        LDA(0, d); LDB(0, d); LDB(1, d);
        STG_A(dn, 1, 128); STG_B(dn, 1, 128);
        BAR_; LGK_; SB0_; MMA(0, 0); MMA(0, 1); BAR_;
        LDA(1, d);
        STG_A(d, 0, 256); STG_B(d, 0, 256);
        BAR_; LGK_; SB0_; MMA(1, 0); MMA(1, 1); VM4_; BAR_;
        gAt += 128; gBt += 128;
    }
    {
        LDA(0, 0); LDB(0, 0); LDB(1, 0);
        STG_A(1, 1, 128); STG_B(1, 1, 128);
        BAR_; LGK_; SB0_; MMA(0, 0); MMA(0, 1); BAR_;
        LDA(1, 0);
        BAR_; LGK_; SB0_; MMA(1, 0); MMA(1, 1); VM0_; BAR_;
    }
    {
        LDA(0, 1); LDB(0, 1); LDB(1, 1);
        BAR_; LGK_; SB0_; MMA(0, 0); MMA(0, 1); BAR_;
        LDA(1, 1);
        BAR_; LGK_; SB0_; MMA(1, 0); MMA(1, 1); BAR_;
    }

    // ---------------- epilogue: two 128-row bounce rounds through LDS -------------
    int blk = (int)(n0 >> 10), nf0 = (int)(n0 & 1023);
    int bB = (int)(m0 >> 12), t0m = (int)(m0 & 4095);
    float bias[4];
#pragma unroll
    for (int j = 0; j < 4; ++j)
        bias[j] = bcat[n0 + (size_t)((j >> 1) * 128 + wn * 32 + (j & 1) * 16 + l15)];
    u16* Cs = (u16*)smem;

#pragma unroll
    for (int h = 0; h < 2; ++h) {
        if (h) __syncthreads();
#pragma unroll
        for (int j = 0; j < 4; ++j) {
            float cs = 0.f;
            int col = (j >> 1) * 128 + wn * 32 + (j & 1) * 16 + l15;
#pragma unroll
            for (int i4 = 0; i4 < 4; ++i4) {
#pragma unroll
                for (int r = 0; r < 4; ++r) {
                    float z = acc[h * 4 + i4][j][r] + bias[j];
                    u16 o;
                    if (blk < 2) {
                        o = f2b(fmaxf(z, 0.f));
                    } else if (blk == 2) {
                        o = f2b(z);
                    } else {
                        float gg = __logf(1.f / (1.f + __expf(-z)) + 1e-6f);
                        o = f2h(gg);
                        cs += gg;
                    }
                    Cs[(wm * 64 + i4 * 16 + quad * 4 + r) * EPITCH + col] = o;
                }
            }
            if (blk == 3) {
                cs += __shfl_xor(cs, 16, 64);
                cs += __shfl_xor(cs, 32, 64);
                if (quad == 0) {
                    int chunk = (t0m >> 6) + h * 2 + wm;
                    part[((size_t)(bB * 64 + chunk) << 10) + nf0 + col] = cs;
                }
            }
        }
        __syncthreads();
        if (blk != 2) {
            u16* dst = (blk == 0) ? qb : (blk == 1) ? kb : gA;
            int lr = tid >> 2, c0 = (tid & 3) * 64;
            size_t rowo = (size_t)(m0 + h * 128 + lr) * 1024 + nf0 + c0;
#pragma unroll
            for (int i = 0; i < 8; ++i)
                *(u16x8*)(dst + rowo + i * 8) = *(const u16x8*)(Cs + lr * EPITCH + c0 + i * 8);
        } else {
            int jc = tid >> 1, th = (tid & 1) * 64;
            size_t rowo = (((size_t)(bB * 1024 + nf0 + jc)) << 12) + t0m + h * 128 + th;
#pragma unroll
            for (int i = 0; i < 8; ++i) {
                u16x8 vv;
#pragma unroll
                for (int e = 0; e < 8; ++e)
                    vv[e] = Cs[(th + i * 8 + e) * EPITCH + jc];
                *(u16x8*)(vT + rowo + i * 8) = vv;
            }
        }
    }
}

// ---------------- gate scan apply (fused suffix-sum of raw chunk partials) ----------
// R8 scalar form restored: 1024 blocks = 4/CU TLP. The serial 64-iter dependent
// chain (load->exp->store) is latency-bound; R19's vec4 collapsed the grid to
// 1/CU and regressed — block-level TLP was the hiding mechanism.
__global__ __launch_bounds__(256) void k_scan_apply(
    const u16* __restrict__ gA, const float* __restrict__ part, u16* __restrict__ kb) {
    int c = blockIdx.x, b = blockIdx.y;
    int col = blockIdx.z * 256 + threadIdx.x;
    float r = 0.f;
    for (int c2 = c + 1; c2 < 64; ++c2)
        r += part[((size_t)(b * 64 + c2) << 10) + col];
    size_t base = (((size_t)(b * TSEQ + c * 64)) << 10) + col;
#pragma unroll 4
    for (int s = 63; s >= 0; --s) {
        size_t ro = base + ((size_t)s << 10);
        r += h2f(gA[ro]);
        kb[ro] = f2b(b2f(kb[ro]) * __expf(r));
    }
}

// ---------------- scores = q @ wk^T (causal), bf16 out + denom atomics ----------------
// R18 dbuf structure kept (best measured).
__global__ __launch_bounds__(256) void k_scores(
    const u16* __restrict__ qb, const u16* __restrict__ wkb,
    u16* __restrict__ scores, float* __restrict__ denom) {
    int bid = blockIdx.x, b = blockIdx.y;
    int xc = bid & 7, idx = bid >> 3;          // idx in [0, 66)
    int rs0 = xc, rs1 = 15 - xc, rs2 = 16 + xc, rs3 = 31 - xc;  // ascending
    int si = 0, rem = idx;
    for (; si < 32; ++si) {
        int n = (rs0 >= si) + (rs1 >= si) + (rs2 >= si) + (rs3 >= si);
        if (rem < n) break;
        rem -= n;
    }
    int ti = rs3, cnt = 0;
    if (rs0 >= si) { if (cnt == rem) ti = rs0; ++cnt; }
    if (rs1 >= si) { if (cnt == rem) ti = rs1; ++cnt; }
    if (rs2 >= si) { if (cnt == rem) ti = rs2; ++cnt; }
    if (rs3 >= si) { if (cnt == rem) ti = rs3; ++cnt; }
    __shared__ __align__(16) char smem[65536];  // A[2][128][64] | B[2][128][64]; bounce overlays
    u16* As = (u16*)smem;
    u16* Bs = (u16*)(smem + 32768);
    int tid = threadIdx.x;
    const u16* A = qb + ((size_t)b << 22);
    const u16* Bm = wkb + ((size_t)b << 22);
    int t0 = ti * 128, s0 = si * 128;
    int wid = tid >> 6, lane = tid & 63;
    int wm = wid >> 1, wn = wid & 1, quad = lane >> 4, l15 = lane & 15;
    int hxor = (lane & 7) ^ (lane >> 3);
    const char* baA = (const char*)A + (size_t)(t0 + wid * 32 + (lane >> 3)) * 2048 + hxor * 16;
    const char* baB = (const char*)Bm + (size_t)(s0 + wid * 32 + (lane >> 3)) * 2048 + hxor * 16;
    f32x4 acc[4][4] = {};
    stage_k(As, baA, 2048, 0, wid, lane);
    stage_k(Bs, baB, 2048, 0, wid, lane);
    KVM0_; KBAR_;
#pragma unroll 2
    for (int t = 0; t < 16; ++t) {
        int cur = t & 1;
        if (t < 15) {
            stage_k(As + (cur ^ 1) * 8192, baA, 2048, (t + 1) * 128, wid, lane);
            stage_k(Bs + (cur ^ 1) * 8192, baB, 2048, (t + 1) * 128, wid, lane);
        }
        mma_tile(As + cur * 8192, Bs + cur * 8192, acc, wm, wn, quad, l15);
        KVM0_; KBAR_;
    }
    u16* Cs = (u16*)smem;
#pragma unroll
    for (int im = 0; im < 4; ++im) {
#pragma unroll
        for (int r = 0; r < 4; ++r) {
            int trow = t0 + wm * 64 + im * 16 + quad * 4 + r;
            float rs = 0.f;
#pragma unroll
            for (int jn = 0; jn < 4; ++jn) {
                int s = s0 + wn * 64 + jn * 16 + l15;
                float val = acc[im][jn][r];
                if (s > trow) val = 0.f;
                rs += val;
                Cs[(wm * 64 + im * 16 + quad * 4 + r) * CPITCH + wn * 64 + jn * 16 + l15] = f2b(val);
            }
#pragma unroll
            for (int m = 1; m < 16; m <<= 1) rs += __shfl_xor(rs, m, 64);
            if (l15 == 0) atomicAdd(denom + (b << 12) + trow, rs);
        }
    }
    __syncthreads();
    int r = tid >> 1, ch = (tid & 1) * 64;
    size_t rowo = ((size_t)(b * TSEQ + t0 + r) << 12) + s0 + ch;
#pragma unroll
    for (int i = 0; i < 8; ++i)
        *(u16x8*)(scores + rowo + i * 8) = *(const u16x8*)(Cs + r * CPITCH + ch + i * 8);
}

// ---------------- num = scores @ v (causal K bound), divide by denom ----------------
// R18 dbuf structure kept.
__global__ __launch_bounds__(256) void k_num(
    const u16* __restrict__ scores, const u16* __restrict__ vT,
    const float* __restrict__ denom, float* __restrict__ out) {
    int ji = blockIdx.x, ti = 31 - blockIdx.y, b = blockIdx.z;
    __shared__ __align__(16) char smem[65536];  // A[2][128][64] | B[2][128][64]
    u16* As = (u16*)smem;
    u16* Bs = (u16*)(smem + 32768);
    int tid = threadIdx.x;
    const u16* A = scores + ((size_t)b << 24);  // [T][T]
    const u16* Bm = vT + ((size_t)b << 22);     // [D][T]
    int t0 = ti * 128, j0 = ji * 128;
    int wid = tid >> 6, lane = tid & 63;
    int wm = wid >> 1, wn = wid & 1, quad = lane >> 4, l15 = lane & 15;
    int hxor = (lane & 7) ^ (lane >> 3);
    const char* pA = (const char*)A + (size_t)(t0 + wid * 32 + (lane >> 3)) * 8192 + hxor * 16;
    const char* pB = (const char*)Bm + (size_t)(j0 + wid * 32 + (lane >> 3)) * 8192 + hxor * 16;
    f32x4 acc[4][4] = {};
    int nt = (ti + 1) * 2;  // BK=64 tiles
    stage_k(As, pA, 8192, 0, wid, lane);
    stage_k(Bs, pB, 8192, 0, wid, lane);
    KVM0_; KBAR_;
    for (int t = 0; t < nt; ++t) {
        int cur = t & 1;
        if (t + 1 < nt) {
            stage_k(As + (cur ^ 1) * 8192, pA, 8192, (t + 1) * 128, wid, lane);
            stage_k(Bs + (cur ^ 1) * 8192, pB, 8192, (t + 1) * 128, wid, lane);
        }
        mma_tile(As + cur * 8192, Bs + cur * 8192, acc, wm, wn, quad, l15);
        KVM0_; KBAR_;
    }
#pragma unroll
    for (int im = 0; im < 4; ++im) {
#pragma unroll
        for (int r = 0; r < 4; ++r) {
            int t = t0 + wm * 64 + im * 16 + quad * 4 + r;
            float den = denom[(b << 12) + t] + EPSV;
#pragma unroll
            for (int jn = 0; jn < 4; ++jn) {
                int j = j0 + wn * 64 + jn * 16 + l15;
                out[((size_t)(b * TSEQ + t) << 10) + j] = acc[im][jn][r] / den;
            }
        }
    }
}

// ---------------- workspace layout (bytes) ----------------
static const size_t OFF_Q      = 0;
static const size_t OFF_WK     = 33554432;
static const size_t OFF_VT     = 67108864;
static const size_t OFF_DENOM  = 100663296;
static const size_t OFF_BCAT   = 100728832;
static const size_t OFF_XW     = 100745216;
static const size_t OFF_WCAT   = 134299648;
static const size_t OFF_GA     = 176242688;   // f16: 33.5 MB
static const size_t OFF_PART   = 243351552;
static const size_t OFF_SCORES = OFF_XW;  // 134,217,728 B, overlays dead early region

extern "C" void kernel_launch(void* const* d_in, const int* in_sizes, int n_in,
                              void* d_out, int out_size, void* d_ws, size_t ws_size,
                              hipStream_t stream) {
    const float* x  = (const float*)d_in[0];
    const float* Wq = (const float*)d_in[1];
    const float* bq = (const float*)d_in[2];
    const float* Wk = (const float*)d_in[3];
    const float* bk = (const float*)d_in[4];
    const float* Wv = (const float*)d_in[5];
    const float* bv = (const float*)d_in[6];
    const float* Wa = (const float*)d_in[7];
    const float* ba = (const float*)d_in[8];
    float* out = (float*)d_out;

    char* W = (char*)d_ws;
    u16* qb      = (u16*)(W + OFF_Q);
    u16* wkb     = (u16*)(W + OFF_WK);
    u16* vT      = (u16*)(W + OFF_VT);
    float* denom = (float*)(W + OFF_DENOM);
    float* bcat  = (float*)(W + OFF_BCAT);
    u16* xw      = (u16*)(W + OFF_XW);
    u16* wcat    = (u16*)(W + OFF_WCAT);
    u16* gA      = (u16*)(W + OFF_GA);
    float* part  = (float*)(W + OFF_PART);
    u16* scores  = (u16*)(W + OFF_SCORES);

    k_prep<<<1282, 256, 0, stream>>>(x, Wq, Wk, Wv, Wa, bq, bk, bv, ba, xw, wcat, bcat, denom);

    k_gemm_qkva<<<dim3(64, 16), 512, 0, stream>>>(xw, wcat, bcat, qb, wkb, vT, gA, part);

    k_scan_apply<<<dim3(64, NB, 4), 256, 0, stream>>>(gA, part, wkb);

    k_scores<<<dim3(528, NB), 256, 0, stream>>>(qb, wkb, scores, denom);

    k_num<<<dim3(8, 32, NB), 256, 0, stream>>>(scores, vT, denom, out);
}